// Round 3
// baseline (172.159 us; speedup 1.0000x reference)
//
#include <hip/hip_runtime.h>
#include <math.h>

#define NPX 4096          // 64*64 low-res pixels per batch
#define H2 128
#define W2 128
#define PP 66             // padded mid plane: 66x66, interior 1..64

// K1: 1x1 conv (256->64) + BN + ReLU into padded mid_p[b][co][66][66].
// grid (128 = 2b x 64 rows, 16 co-groups of 4), block 256 = 4 ci-quarter waves.
// v3: epilogue also zeroes the pad border (row 0/65 by y==0 blocks, side
// cols by every row block) -> the hipMemsetAsync dispatch is gone.
__global__ __launch_bounds__(256) void k1_conv1x1(
    const float* __restrict__ X, const float* __restrict__ w,
    const float* __restrict__ g, const float* __restrict__ bt,
    const float* __restrict__ m, const float* __restrict__ var,
    float* __restrict__ mid_p)
{
    __shared__ float red[3 * 4 * 64];   // 3 KB
    int tid = threadIdx.x;
    int x = tid & 63;
    int ciq = __builtin_amdgcn_readfirstlane(tid >> 6);   // 0..3
    int bx = blockIdx.x;
    int bb = bx >> 6, y = bx & 63;
    int co0 = blockIdx.y * 4;
    int ci0 = ciq * 64;

    const float* xp = X + ((size_t)(bb * 256 + ci0)) * NPX + y * 64 + x;
    const float* wp = w + (size_t)co0 * 256 + ci0;   // uniform -> s_load

    float acc[4] = {0.f, 0.f, 0.f, 0.f};

    #pragma unroll 8
    for (int ci = 0; ci < 64; ++ci) {
        float xv = xp[(size_t)ci * NPX];
        #pragma unroll
        for (int j = 0; j < 4; ++j)
            acc[j] += xv * wp[j * 256 + ci];
    }

    if (ciq > 0) {
        #pragma unroll
        for (int j = 0; j < 4; ++j)
            red[((ciq - 1) * 4 + j) * 64 + x] = acc[j];
    }
    __syncthreads();
    if (ciq == 0) {
        #pragma unroll
        for (int j = 0; j < 4; ++j) {
            float a = acc[j] + red[(0 * 4 + j) * 64 + x]
                             + red[(1 * 4 + j) * 64 + x]
                             + red[(2 * 4 + j) * 64 + x];
            int co = co0 + j;
            float inv = g[co] * rsqrtf(var[co] + 1e-5f);
            a = fmaxf(a * inv + (bt[co] - m[co] * inv), 0.f);
            float* pl = mid_p + (size_t)(bb * 64 + co) * PP * PP;
            pl[(size_t)(y + 1) * PP + (x + 1)] = a;
            // pad-zeroing (replaces memset):
            if (x == 0) {                       // side cols of this row
                pl[(size_t)(y + 1) * PP] = 0.f;
                pl[(size_t)(y + 1) * PP + 65] = 0.f;
            }
            if (y == 0) {                       // full top/bottom pad rows
                pl[x] = 0.f;
                pl[(size_t)65 * PP + x] = 0.f;
                if (x < 2) {
                    pl[64 + x] = 0.f;
                    pl[(size_t)65 * PP + 64 + x] = 0.f;
                }
            }
        }
    }
}

// K2 fused: 3x3 conv (64->100) + BN + clamp + pow + softmax -> wn, one kernel.
// Key: softmax for sub-position s needs exactly co in {4k+s, k=0..24}.
// grid (128 = 2b x 64 rows, 4 s-blocks), block 256 = 4 ci-quarter waves,
// each wave acc[25] over its 16 ci; cross-wave reduce (same order as before:
// accq0 + red_q1 + red_q2 + red_q3 -> bit-identical); ciq==0 wave then runs
// the per-lane softmax in-register and stores wn directly.
// Removes: enc write+read (6.6 MB L2), the K2b dispatch, and cuts mid_p
// window re-reads 10x -> 4x (188 -> 75 MB).
__global__ __launch_bounds__(256) void k2_fused(
    const float* __restrict__ mid_p, const float* __restrict__ ew,
    const float* __restrict__ g, const float* __restrict__ bt,
    const float* __restrict__ m, const float* __restrict__ var,
    const float* __restrict__ power_p,
    float* __restrict__ wn)
{
    __shared__ float red[3 * 25 * 64];   // 19.2 KB
    int tid = threadIdx.x;
    int x = tid & 63;
    int ciq = __builtin_amdgcn_readfirstlane(tid >> 6);   // 0..3
    int bx = blockIdx.x;
    int bb = bx >> 6, y = bx & 63;
    int s = blockIdx.y;                  // 0..3 sub-position

    float acc[25];
    #pragma unroll
    for (int k = 0; k < 25; ++k) acc[k] = 0.f;

    // ew[co][ci][9], co = 4k+s -> k-stride 4*576, ci base (ciq*16)*9. Uniform.
    const float* wb = ew + ((size_t)s * 64 + ciq * 16) * 9;

    #pragma unroll 1
    for (int ci = 0; ci < 16; ++ci) {
        const float* P = mid_p + (((size_t)(bb * 64 + ciq * 16 + ci)) * PP + y) * PP + x;
        float v0 = P[0],       v1 = P[1],          v2 = P[2];
        float v3 = P[PP],      v4 = P[PP + 1],     v5 = P[PP + 2];
        float v6 = P[2 * PP],  v7 = P[2 * PP + 1], v8 = P[2 * PP + 2];
        const float* wp = wb + ci * 9;
        #pragma unroll
        for (int k = 0; k < 25; ++k) {
            const float* wj = wp + (size_t)k * 4 * 576;   // co step = 4 planes
            acc[k] += v0 * wj[0] + v1 * wj[1] + v2 * wj[2]
                    + v3 * wj[3] + v4 * wj[4] + v5 * wj[5]
                    + v6 * wj[6] + v7 * wj[7] + v8 * wj[8];
        }
    }

    if (ciq > 0) {
        #pragma unroll
        for (int k = 0; k < 25; ++k)
            red[((ciq - 1) * 25 + k) * 64 + x] = acc[k];
    }
    __syncthreads();
    if (ciq == 0) {
        float pw = fmaxf(power_p[0], 1e-5f);
        float tv[25];
        float mx = -1e30f;
        #pragma unroll
        for (int k = 0; k < 25; ++k) {
            float a = acc[k] + red[(0 * 25 + k) * 64 + x]
                             + red[(1 * 25 + k) * 64 + x]
                             + red[(2 * 25 + k) * 64 + x];
            int co = 4 * k + s;
            float inv = g[co] * rsqrtf(var[co] + 1e-5f);
            float e = a * inv + (bt[co] - m[co] * inv);
            e = fmaxf(e, 1e-5f);
            float xq = exp2f(pw * log2f(e));
            tv[k] = xq;
            mx = fmaxf(mx, xq);
        }
        float sum = 0.f;
        #pragma unroll
        for (int k = 0; k < 25; ++k) {
            float e = expf(tv[k] - mx);
            tv[k] = e;
            sum += e;
        }
        float r = 1.0f / sum;
        #pragma unroll
        for (int k = 0; k < 25; ++k)
            wn[((size_t)bb * 100 + s * 25 + k) * NPX + y * 64 + x] = tv[k] * r;
    }
}

// K3 v3 (proven): reassembly, tap-major. grid (128 = 2b x 64 rows, 16 ch-groups),
// block 256 = 4 waves; wave = CHANNEL QUAD, lane = px. UNCHANGED.
__global__ __launch_bounds__(256) void k3_carafe(
    const float* __restrict__ X, const float* __restrict__ wn,
    float* __restrict__ out)
{
    __shared__ float xt[16 * 5 * 72];   // 23 KB
    int tid = threadIdx.x;
    int px = tid & 63;
    int bx = blockIdx.x;
    int bb = bx >> 6, y = bx & 63;
    int c0 = blockIdx.y * 16;

    // stage X halo: [ch][r][72], r = y-2..y+2, c stores gx = c-2
    for (int idx = tid; idx < 5760; idx += 256) {
        int ch = idx / 360;
        int rem = idx - ch * 360;
        int r = rem / 72, c = rem - r * 72;
        int gy = y + r - 2, gx = c - 2;
        float val = 0.f;
        if (c < 68 && (unsigned)gy < 64u && (unsigned)gx < 64u)
            val = X[((size_t)(bb * 256 + c0 + ch)) * NPX + gy * 64 + gx];
        xt[idx] = val;
    }
    __syncthreads();

    int wq = __builtin_amdgcn_readfirstlane(tid >> 6);   // 0..3 channel quad

    float a[4][4];   // [cc][s], statically indexed -> registers
    #pragma unroll
    for (int i = 0; i < 4; ++i)
        #pragma unroll
        for (int j = 0; j < 4; ++j) a[i][j] = 0.f;

    const float* wbase = wn + ((size_t)bb * 100) * NPX + y * 64 + px;
    const float* xbase = xt + wq * 4 * 360 + px;

    #pragma unroll 1
    for (int ki = 0; ki < 5; ++ki) {
        #pragma unroll
        for (int kj = 0; kj < 5; ++kj) {
            int k = ki * 5 + kj;
            float w0 = wbase[(size_t)(k)      * NPX];
            float w1 = wbase[(size_t)(25 + k) * NPX];
            float w2 = wbase[(size_t)(50 + k) * NPX];
            float w3 = wbase[(size_t)(75 + k) * NPX];
            #pragma unroll
            for (int cc = 0; cc < 4; ++cc) {
                float v = xbase[cc * 360 + ki * 72 + kj];
                a[cc][0] += w0 * v;
                a[cc][1] += w1 * v;
                a[cc][2] += w2 * v;
                a[cc][3] += w3 * v;
            }
        }
    }

    #pragma unroll
    for (int cc = 0; cc < 4; ++cc) {
        int ch = wq * 4 + cc;
        float* ob = out + ((size_t)(bb * 256 + c0 + ch) * H2 + 2 * y) * W2 + 2 * px;
        ((float2*)ob)[0]        = make_float2(a[cc][0], a[cc][1]);   // row 2y
        ((float2*)(ob + W2))[0] = make_float2(a[cc][2], a[cc][3]);   // row 2y+1
    }
}

extern "C" void kernel_launch(void* const* d_in, const int* in_sizes, int n_in,
                              void* d_out, int out_size, void* d_ws, size_t ws_size,
                              hipStream_t stream)
{
    const float* X  = (const float*)d_in[0];
    const float* cw = (const float*)d_in[1];
    const float* cg = (const float*)d_in[2];
    const float* cb = (const float*)d_in[3];
    const float* cm = (const float*)d_in[4];
    const float* cv = (const float*)d_in[5];
    const float* ew = (const float*)d_in[6];
    const float* eg = (const float*)d_in[7];
    const float* eb = (const float*)d_in[8];
    const float* em = (const float*)d_in[9];
    const float* ev = (const float*)d_in[10];
    const float* pp = (const float*)d_in[11];
    float* out = (float*)d_out;

    float* ws   = (float*)d_ws;
    float* midp = ws;                         // 2*64*66*66 = 557,568 floats (padded)
    float* wn   = ws + 557568;                // 2*100*4096 = 819,200 floats

    k1_conv1x1<<<dim3(128, 16), 256, 0, stream>>>(X, cw, cg, cb, cm, cv, midp);
    k2_fused<<<dim3(128, 4), 256, 0, stream>>>(midp, ew, eg, eb, em, ev, pp, wn);
    k3_carafe<<<dim3(128, 16), 256, 0, stream>>>(X, wn, out);
}

// Round 5
// 153.118 us; speedup vs baseline: 1.1244x; 1.1244x over previous
//
#include <hip/hip_runtime.h>
#include <math.h>

#define NPX 4096          // 64*64 low-res pixels per batch
#define H2 128
#define W2 128
#define PP 66             // padded mid plane: 66x66, interior 1..64

// K1: 1x1 conv (256->64) + BN + ReLU into padded mid_p[b][co][66][66].
// grid (128 = 2b x 64 rows, 16 co-groups of 4), block 256 = 4 ci-quarter waves.
// Epilogue zeroes the pad border -> no memset dispatch. Weight slab
// 4*256*4B = 4 KB -> scalar-L1 resident.
__global__ __launch_bounds__(256) void k1_conv1x1(
    const float* __restrict__ X, const float* __restrict__ w,
    const float* __restrict__ g, const float* __restrict__ bt,
    const float* __restrict__ m, const float* __restrict__ var,
    float* __restrict__ mid_p)
{
    __shared__ float red[3 * 4 * 64];   // 3 KB
    int tid = threadIdx.x;
    int x = tid & 63;
    int ciq = __builtin_amdgcn_readfirstlane(tid >> 6);   // 0..3
    int bx = blockIdx.x;
    int bb = bx >> 6, y = bx & 63;
    int co0 = blockIdx.y * 4;
    int ci0 = ciq * 64;

    const float* xp = X + ((size_t)(bb * 256 + ci0)) * NPX + y * 64 + x;
    const float* wp = w + (size_t)co0 * 256 + ci0;   // uniform -> s_load

    float acc[4] = {0.f, 0.f, 0.f, 0.f};

    #pragma unroll 8
    for (int ci = 0; ci < 64; ++ci) {
        float xv = xp[(size_t)ci * NPX];
        #pragma unroll
        for (int j = 0; j < 4; ++j)
            acc[j] += xv * wp[j * 256 + ci];
    }

    if (ciq > 0) {
        #pragma unroll
        for (int j = 0; j < 4; ++j)
            red[((ciq - 1) * 4 + j) * 64 + x] = acc[j];
    }
    __syncthreads();
    if (ciq == 0) {
        #pragma unroll
        for (int j = 0; j < 4; ++j) {
            float a = acc[j] + red[(0 * 4 + j) * 64 + x]
                             + red[(1 * 4 + j) * 64 + x]
                             + red[(2 * 4 + j) * 64 + x];
            int co = co0 + j;
            float inv = g[co] * rsqrtf(var[co] + 1e-5f);
            a = fmaxf(a * inv + (bt[co] - m[co] * inv), 0.f);
            float* pl = mid_p + (size_t)(bb * 64 + co) * PP * PP;
            pl[(size_t)(y + 1) * PP + (x + 1)] = a;
            // pad-zeroing (replaces memset):
            if (x == 0) {                       // side cols of this row
                pl[(size_t)(y + 1) * PP] = 0.f;
                pl[(size_t)(y + 1) * PP + 65] = 0.f;
            }
            if (y == 0) {                       // full top/bottom pad rows
                pl[x] = 0.f;
                pl[(size_t)65 * PP + x] = 0.f;
                if (x < 2) {
                    pl[64 + x] = 0.f;
                    pl[(size_t)65 * PP + 64 + x] = 0.f;
                }
            }
        }
    }
}

// K2a v2: 3x3 conv (64->100), co-groups of 5 (was 10).
// Why: round-3 attribution put k2a at ~27-30 us with ~20% VALUBusy — the
// co-10 weight slab (23 KB) overflows the 16 KB scalar L1, so the 90-float
// per-ci s_load stream misses to L2 and every wave stalls on lgkm chains.
// co-5: slab 11.5 KB (sL1-resident), 45 floats/ci window, grid (128,20) =
// 2560 blocks -> 8 waves/SIMD (was 5). Per-co summation order identical
// (same ciq quarters, same reduce) -> bit-identical enc.
__global__ __launch_bounds__(256) void k2a_conv3x3(
    const float* __restrict__ mid_p, const float* __restrict__ ew,
    float* __restrict__ enc)
{
    __shared__ float red[3 * 5 * 64];   // 3.8 KB
    int tid = threadIdx.x;
    int x = tid & 63;
    int ciq = __builtin_amdgcn_readfirstlane(tid >> 6);   // 0..3
    int bx = blockIdx.x;
    int bb = bx >> 6, y = bx & 63;
    int co0 = blockIdx.y * 5;

    float acc[5];
    #pragma unroll
    for (int j = 0; j < 5; ++j) acc[j] = 0.f;

    const float* wb = ew + ((size_t)co0 * 64 + ciq * 16) * 9;   // uniform

    #pragma unroll 2
    for (int ci = 0; ci < 16; ++ci) {
        const float* P = mid_p + (((size_t)(bb * 64 + ciq * 16 + ci)) * PP + y) * PP + x;
        float v0 = P[0],       v1 = P[1],          v2 = P[2];
        float v3 = P[PP],      v4 = P[PP + 1],     v5 = P[PP + 2];
        float v6 = P[2 * PP],  v7 = P[2 * PP + 1], v8 = P[2 * PP + 2];
        const float* wp = wb + ci * 9;          // j stride = 64*9 = 576
        #pragma unroll
        for (int j = 0; j < 5; ++j) {
            const float* wj = wp + j * 576;
            acc[j] += v0 * wj[0] + v1 * wj[1] + v2 * wj[2]
                    + v3 * wj[3] + v4 * wj[4] + v5 * wj[5]
                    + v6 * wj[6] + v7 * wj[7] + v8 * wj[8];
        }
    }

    if (ciq > 0) {
        #pragma unroll
        for (int j = 0; j < 5; ++j)
            red[((ciq - 1) * 5 + j) * 64 + x] = acc[j];
    }
    __syncthreads();
    if (ciq == 0) {
        #pragma unroll
        for (int j = 0; j < 5; ++j) {
            float a = acc[j] + red[(0 * 5 + j) * 64 + x]
                             + red[(1 * 5 + j) * 64 + x]
                             + red[(2 * 5 + j) * 64 + x];
            enc[((size_t)bb * 100 + co0 + j) * NPX + y * 64 + x] = a;
        }
    }
}

// K2b: BN + clamp + pow + softmax over 25 taps. wn layout [b][s*25+k][px].
// UNCHANGED (proven, small).
__global__ __launch_bounds__(64) void k2b_softmax(
    const float* __restrict__ enc,
    const float* __restrict__ g, const float* __restrict__ bt,
    const float* __restrict__ m, const float* __restrict__ var,
    const float* __restrict__ power_p,
    float* __restrict__ wn)
{
    int s = blockIdx.x & 3;
    int p = (blockIdx.x >> 2) * 64 + threadIdx.x;
    int bb = p >> 12, sp = p & (NPX - 1);
    float pw = fmaxf(power_p[0], 1e-5f);
    float tv[25];
    float mx = -1e30f;
    #pragma unroll
    for (int k = 0; k < 25; ++k) {
        int co = 4 * k + s;
        float inv = g[co] * rsqrtf(var[co] + 1e-5f);
        float e = enc[((size_t)bb * 100 + co) * NPX + sp] * inv + (bt[co] - m[co] * inv);
        e = fmaxf(e, 1e-5f);
        float xq = exp2f(pw * log2f(e));
        tv[k] = xq;
        mx = fmaxf(mx, xq);
    }
    float sum = 0.f;
    #pragma unroll
    for (int k = 0; k < 25; ++k) {
        float e = expf(tv[k] - mx);
        tv[k] = e;
        sum += e;
    }
    float r = 1.0f / sum;
    #pragma unroll
    for (int k = 0; k < 25; ++k)
        wn[((size_t)bb * 100 + s * 25 + k) * NPX + sp] = tv[k] * r;
}

// K3 v3 (proven): reassembly, tap-major. grid (128 = 2b x 64 rows, 16 ch-groups),
// block 256 = 4 waves; wave = CHANNEL QUAD, lane = px. UNCHANGED.
__global__ __launch_bounds__(256) void k3_carafe(
    const float* __restrict__ X, const float* __restrict__ wn,
    float* __restrict__ out)
{
    __shared__ float xt[16 * 5 * 72];   // 23 KB
    int tid = threadIdx.x;
    int px = tid & 63;
    int bx = blockIdx.x;
    int bb = bx >> 6, y = bx & 63;
    int c0 = blockIdx.y * 16;

    // stage X halo: [ch][r][72], r = y-2..y+2, c stores gx = c-2
    for (int idx = tid; idx < 5760; idx += 256) {
        int ch = idx / 360;
        int rem = idx - ch * 360;
        int r = rem / 72, c = rem - r * 72;
        int gy = y + r - 2, gx = c - 2;
        float val = 0.f;
        if (c < 68 && (unsigned)gy < 64u && (unsigned)gx < 64u)
            val = X[((size_t)(bb * 256 + c0 + ch)) * NPX + gy * 64 + gx];
        xt[idx] = val;
    }
    __syncthreads();

    int wq = __builtin_amdgcn_readfirstlane(tid >> 6);   // 0..3 channel quad

    float a[4][4];   // [cc][s], statically indexed -> registers
    #pragma unroll
    for (int i = 0; i < 4; ++i)
        #pragma unroll
        for (int j = 0; j < 4; ++j) a[i][j] = 0.f;

    const float* wbase = wn + ((size_t)bb * 100) * NPX + y * 64 + px;
    const float* xbase = xt + wq * 4 * 360 + px;

    #pragma unroll 1
    for (int ki = 0; ki < 5; ++ki) {
        #pragma unroll
        for (int kj = 0; kj < 5; ++kj) {
            int k = ki * 5 + kj;
            float w0 = wbase[(size_t)(k)      * NPX];
            float w1 = wbase[(size_t)(25 + k) * NPX];
            float w2 = wbase[(size_t)(50 + k) * NPX];
            float w3 = wbase[(size_t)(75 + k) * NPX];
            #pragma unroll
            for (int cc = 0; cc < 4; ++cc) {
                float v = xbase[cc * 360 + ki * 72 + kj];
                a[cc][0] += w0 * v;
                a[cc][1] += w1 * v;
                a[cc][2] += w2 * v;
                a[cc][3] += w3 * v;
            }
        }
    }

    #pragma unroll
    for (int cc = 0; cc < 4; ++cc) {
        int ch = wq * 4 + cc;
        float* ob = out + ((size_t)(bb * 256 + c0 + ch) * H2 + 2 * y) * W2 + 2 * px;
        ((float2*)ob)[0]        = make_float2(a[cc][0], a[cc][1]);   // row 2y
        ((float2*)(ob + W2))[0] = make_float2(a[cc][2], a[cc][3]);   // row 2y+1
    }
}

extern "C" void kernel_launch(void* const* d_in, const int* in_sizes, int n_in,
                              void* d_out, int out_size, void* d_ws, size_t ws_size,
                              hipStream_t stream)
{
    const float* X  = (const float*)d_in[0];
    const float* cw = (const float*)d_in[1];
    const float* cg = (const float*)d_in[2];
    const float* cb = (const float*)d_in[3];
    const float* cm = (const float*)d_in[4];
    const float* cv = (const float*)d_in[5];
    const float* ew = (const float*)d_in[6];
    const float* eg = (const float*)d_in[7];
    const float* eb = (const float*)d_in[8];
    const float* em = (const float*)d_in[9];
    const float* ev = (const float*)d_in[10];
    const float* pp = (const float*)d_in[11];
    float* out = (float*)d_out;

    float* ws   = (float*)d_ws;
    float* midp = ws;                         // 2*64*66*66 = 557,568 floats (padded)
    float* enc  = ws + 557568;                // 2*100*4096 = 819,200 floats
    float* wn   = ws + 557568 + 819200;       // 2*100*4096 = 819,200 floats

    k1_conv1x1<<<dim3(128, 16), 256, 0, stream>>>(X, cw, cg, cb, cm, cv, midp);
    k2a_conv3x3<<<dim3(128, 20), 256, 0, stream>>>(midp, ew, enc);
    k2b_softmax<<<dim3(512), 64, 0, stream>>>(enc, eg, eb, em, ev, pp, wn);
    k3_carafe<<<dim3(128, 16), 256, 0, stream>>>(X, wn, out);
}

// Round 6
// 152.167 us; speedup vs baseline: 1.1314x; 1.0063x over previous
//
#include <hip/hip_runtime.h>
#include <math.h>

#define NPX 4096          // 64*64 low-res pixels per batch
#define H2 128
#define W2 128
#define PP 66             // padded mid plane: 66x66, interior 1..64

// K1 v4: 1x1 conv (256->64) + BN + ReLU into padded mid_p[b][co][66][66].
// co-groups of 8 (was 4): X re-read 16x -> 8x (134 -> 67 MB of L3 traffic;
// X @ 8.4 MB doesn't fit a 4-MiB per-XCD L2, so re-reads are L3-bound).
// grid (128 = 2b x 64 rows, 8 co-groups), block 256 = 4 ci-quarter waves ->
// 4096 waves = 4/SIMD (unroll-8 keeps 32 loads in flight per SIMD).
// acc[8] + 64-float scalar window ~50 VGPR (round-1's co-16 spill was 16 acc).
// Per-co summation order identical to proven co-4 -> bit-identical mid_p.
// Epilogue zeroes the pad border -> no memset dispatch.
__global__ __launch_bounds__(256) void k1_conv1x1(
    const float* __restrict__ X, const float* __restrict__ w,
    const float* __restrict__ g, const float* __restrict__ bt,
    const float* __restrict__ m, const float* __restrict__ var,
    float* __restrict__ mid_p)
{
    __shared__ float red[3 * 8 * 64];   // 6 KB
    int tid = threadIdx.x;
    int x = tid & 63;
    int ciq = __builtin_amdgcn_readfirstlane(tid >> 6);   // 0..3
    int bx = blockIdx.x;
    int bb = bx >> 6, y = bx & 63;
    int co0 = blockIdx.y * 8;
    int ci0 = ciq * 64;

    const float* xp = X + ((size_t)(bb * 256 + ci0)) * NPX + y * 64 + x;
    const float* wp = w + (size_t)co0 * 256 + ci0;   // uniform -> s_load

    float acc[8];
    #pragma unroll
    for (int j = 0; j < 8; ++j) acc[j] = 0.f;

    #pragma unroll 8
    for (int ci = 0; ci < 64; ++ci) {
        float xv = xp[(size_t)ci * NPX];
        #pragma unroll
        for (int j = 0; j < 8; ++j)
            acc[j] += xv * wp[j * 256 + ci];
    }

    if (ciq > 0) {
        #pragma unroll
        for (int j = 0; j < 8; ++j)
            red[((ciq - 1) * 8 + j) * 64 + x] = acc[j];
    }
    __syncthreads();
    if (ciq == 0) {
        #pragma unroll
        for (int j = 0; j < 8; ++j) {
            float a = acc[j] + red[(0 * 8 + j) * 64 + x]
                             + red[(1 * 8 + j) * 64 + x]
                             + red[(2 * 8 + j) * 64 + x];
            int co = co0 + j;
            float inv = g[co] * rsqrtf(var[co] + 1e-5f);
            a = fmaxf(a * inv + (bt[co] - m[co] * inv), 0.f);
            float* pl = mid_p + (size_t)(bb * 64 + co) * PP * PP;
            pl[(size_t)(y + 1) * PP + (x + 1)] = a;
            // pad-zeroing (replaces memset):
            if (x == 0) {                       // side cols of this row
                pl[(size_t)(y + 1) * PP] = 0.f;
                pl[(size_t)(y + 1) * PP + 65] = 0.f;
            }
            if (y == 0) {                       // full top/bottom pad rows
                pl[x] = 0.f;
                pl[(size_t)65 * PP + x] = 0.f;
                if (x < 2) {
                    pl[64 + x] = 0.f;
                    pl[(size_t)65 * PP + 64 + x] = 0.f;
                }
            }
        }
    }
}

// K2a v2 (proven == co-10 within noise): 3x3 conv (64->100), co-groups of 5.
// grid (128, 20), block 256 = 4 ci-quarter waves. UNCHANGED control.
__global__ __launch_bounds__(256) void k2a_conv3x3(
    const float* __restrict__ mid_p, const float* __restrict__ ew,
    float* __restrict__ enc)
{
    __shared__ float red[3 * 5 * 64];   // 3.8 KB
    int tid = threadIdx.x;
    int x = tid & 63;
    int ciq = __builtin_amdgcn_readfirstlane(tid >> 6);   // 0..3
    int bx = blockIdx.x;
    int bb = bx >> 6, y = bx & 63;
    int co0 = blockIdx.y * 5;

    float acc[5];
    #pragma unroll
    for (int j = 0; j < 5; ++j) acc[j] = 0.f;

    const float* wb = ew + ((size_t)co0 * 64 + ciq * 16) * 9;   // uniform

    #pragma unroll 2
    for (int ci = 0; ci < 16; ++ci) {
        const float* P = mid_p + (((size_t)(bb * 64 + ciq * 16 + ci)) * PP + y) * PP + x;
        float v0 = P[0],       v1 = P[1],          v2 = P[2];
        float v3 = P[PP],      v4 = P[PP + 1],     v5 = P[PP + 2];
        float v6 = P[2 * PP],  v7 = P[2 * PP + 1], v8 = P[2 * PP + 2];
        const float* wp = wb + ci * 9;          // j stride = 64*9 = 576
        #pragma unroll
        for (int j = 0; j < 5; ++j) {
            const float* wj = wp + j * 576;
            acc[j] += v0 * wj[0] + v1 * wj[1] + v2 * wj[2]
                    + v3 * wj[3] + v4 * wj[4] + v5 * wj[5]
                    + v6 * wj[6] + v7 * wj[7] + v8 * wj[8];
        }
    }

    if (ciq > 0) {
        #pragma unroll
        for (int j = 0; j < 5; ++j)
            red[((ciq - 1) * 5 + j) * 64 + x] = acc[j];
    }
    __syncthreads();
    if (ciq == 0) {
        #pragma unroll
        for (int j = 0; j < 5; ++j) {
            float a = acc[j] + red[(0 * 5 + j) * 64 + x]
                             + red[(1 * 5 + j) * 64 + x]
                             + red[(2 * 5 + j) * 64 + x];
            enc[((size_t)bb * 100 + co0 + j) * NPX + y * 64 + x] = a;
        }
    }
}

// K2b: BN + clamp + pow + softmax over 25 taps. wn layout [b][s*25+k][px].
// UNCHANGED (proven, small).
__global__ __launch_bounds__(64) void k2b_softmax(
    const float* __restrict__ enc,
    const float* __restrict__ g, const float* __restrict__ bt,
    const float* __restrict__ m, const float* __restrict__ var,
    const float* __restrict__ power_p,
    float* __restrict__ wn)
{
    int s = blockIdx.x & 3;
    int p = (blockIdx.x >> 2) * 64 + threadIdx.x;
    int bb = p >> 12, sp = p & (NPX - 1);
    float pw = fmaxf(power_p[0], 1e-5f);
    float tv[25];
    float mx = -1e30f;
    #pragma unroll
    for (int k = 0; k < 25; ++k) {
        int co = 4 * k + s;
        float inv = g[co] * rsqrtf(var[co] + 1e-5f);
        float e = enc[((size_t)bb * 100 + co) * NPX + sp] * inv + (bt[co] - m[co] * inv);
        e = fmaxf(e, 1e-5f);
        float xq = exp2f(pw * log2f(e));
        tv[k] = xq;
        mx = fmaxf(mx, xq);
    }
    float sum = 0.f;
    #pragma unroll
    for (int k = 0; k < 25; ++k) {
        float e = expf(tv[k] - mx);
        tv[k] = e;
        sum += e;
    }
    float r = 1.0f / sum;
    #pragma unroll
    for (int k = 0; k < 25; ++k)
        wn[((size_t)bb * 100 + s * 25 + k) * NPX + sp] = tv[k] * r;
}

// K3 v3 (proven): reassembly, tap-major. grid (128 = 2b x 64 rows, 16 ch-groups),
// block 256 = 4 waves; wave = CHANNEL QUAD, lane = px. UNCHANGED control.
__global__ __launch_bounds__(256) void k3_carafe(
    const float* __restrict__ X, const float* __restrict__ wn,
    float* __restrict__ out)
{
    __shared__ float xt[16 * 5 * 72];   // 23 KB
    int tid = threadIdx.x;
    int px = tid & 63;
    int bx = blockIdx.x;
    int bb = bx >> 6, y = bx & 63;
    int c0 = blockIdx.y * 16;

    // stage X halo: [ch][r][72], r = y-2..y+2, c stores gx = c-2
    for (int idx = tid; idx < 5760; idx += 256) {
        int ch = idx / 360;
        int rem = idx - ch * 360;
        int r = rem / 72, c = rem - r * 72;
        int gy = y + r - 2, gx = c - 2;
        float val = 0.f;
        if (c < 68 && (unsigned)gy < 64u && (unsigned)gx < 64u)
            val = X[((size_t)(bb * 256 + c0 + ch)) * NPX + gy * 64 + gx];
        xt[idx] = val;
    }
    __syncthreads();

    int wq = __builtin_amdgcn_readfirstlane(tid >> 6);   // 0..3 channel quad

    float a[4][4];   // [cc][s], statically indexed -> registers
    #pragma unroll
    for (int i = 0; i < 4; ++i)
        #pragma unroll
        for (int j = 0; j < 4; ++j) a[i][j] = 0.f;

    const float* wbase = wn + ((size_t)bb * 100) * NPX + y * 64 + px;
    const float* xbase = xt + wq * 4 * 360 + px;

    #pragma unroll 1
    for (int ki = 0; ki < 5; ++ki) {
        #pragma unroll
        for (int kj = 0; kj < 5; ++kj) {
            int k = ki * 5 + kj;
            float w0 = wbase[(size_t)(k)      * NPX];
            float w1 = wbase[(size_t)(25 + k) * NPX];
            float w2 = wbase[(size_t)(50 + k) * NPX];
            float w3 = wbase[(size_t)(75 + k) * NPX];
            #pragma unroll
            for (int cc = 0; cc < 4; ++cc) {
                float v = xbase[cc * 360 + ki * 72 + kj];
                a[cc][0] += w0 * v;
                a[cc][1] += w1 * v;
                a[cc][2] += w2 * v;
                a[cc][3] += w3 * v;
            }
        }
    }

    #pragma unroll
    for (int cc = 0; cc < 4; ++cc) {
        int ch = wq * 4 + cc;
        float* ob = out + ((size_t)(bb * 256 + c0 + ch) * H2 + 2 * y) * W2 + 2 * px;
        ((float2*)ob)[0]        = make_float2(a[cc][0], a[cc][1]);   // row 2y
        ((float2*)(ob + W2))[0] = make_float2(a[cc][2], a[cc][3]);   // row 2y+1
    }
}

extern "C" void kernel_launch(void* const* d_in, const int* in_sizes, int n_in,
                              void* d_out, int out_size, void* d_ws, size_t ws_size,
                              hipStream_t stream)
{
    const float* X  = (const float*)d_in[0];
    const float* cw = (const float*)d_in[1];
    const float* cg = (const float*)d_in[2];
    const float* cb = (const float*)d_in[3];
    const float* cm = (const float*)d_in[4];
    const float* cv = (const float*)d_in[5];
    const float* ew = (const float*)d_in[6];
    const float* eg = (const float*)d_in[7];
    const float* eb = (const float*)d_in[8];
    const float* em = (const float*)d_in[9];
    const float* ev = (const float*)d_in[10];
    const float* pp = (const float*)d_in[11];
    float* out = (float*)d_out;

    float* ws   = (float*)d_ws;
    float* midp = ws;                         // 2*64*66*66 = 557,568 floats (padded)
    float* enc  = ws + 557568;                // 2*100*4096 = 819,200 floats
    float* wn   = ws + 557568 + 819200;       // 2*100*4096 = 819,200 floats

    k1_conv1x1<<<dim3(128, 8), 256, 0, stream>>>(X, cw, cg, cb, cm, cv, midp);
    k2a_conv3x3<<<dim3(128, 20), 256, 0, stream>>>(midp, ew, enc);
    k2b_softmax<<<dim3(512), 64, 0, stream>>>(enc, eg, eb, em, ev, pp, wn);
    k3_carafe<<<dim3(128, 16), 256, 0, stream>>>(X, wn, out);
}